// Round 4
// baseline (6927.144 us; speedup 1.0000x reference)
//
#include <hip/hip_runtime.h>
#include <hip/hip_bf16.h>
#include <hip/hip_fp16.h>

typedef __attribute__((ext_vector_type(8))) short s16x8;
typedef __attribute__((ext_vector_type(8))) _Float16 f16x8;
typedef __attribute__((ext_vector_type(4))) float f32x4;

// ---------------------------------------------------------------------------
// fp32 -> fp16 conversion (vectorized, grid-stride)
// ---------------------------------------------------------------------------
__global__ void cvt_f32_to_f16_kernel(const float* __restrict__ in,
                                      __half* __restrict__ out,
                                      long n) {
  long i = (long)blockIdx.x * blockDim.x + threadIdx.x;
  long stride = (long)gridDim.x * blockDim.x;
  const float4* p4 = (const float4*)in;
  for (long j = i; j * 8 < n; j += stride) {
    float4 a = p4[j * 2];
    float4 b = p4[j * 2 + 1];
    union { s16x8 v; __half2 h2[4]; } w;
    w.h2[0] = __floats2half2_rn(a.x, a.y);
    w.h2[1] = __floats2half2_rn(a.z, a.w);
    w.h2[2] = __floats2half2_rn(b.x, b.y);
    w.h2[3] = __floats2half2_rn(b.z, b.w);
    *(s16x8*)(out + j * 8) = w.v;
  }
}

// ---------------------------------------------------------------------------
// Dequant 8 int4-in-int32 -> 8 fp16 via bit-trick + pk_fma.
// f16(64+q) = 0x5400 | (q<<4);  w = b*s - (64+z)*s
// ---------------------------------------------------------------------------
__device__ __forceinline__ s16x8 dq_compute(int4 q0, int4 q1, float s, float z) {
  __half hs = __float2half(s);
  __half2 s2 = __halves2half2(hs, hs);
  __half hc = __float2half(-(64.f + z) * s);
  __half2 c2 = __halves2half2(hc, hc);
  uint32_t b0 = 0x54005400u + ((uint32_t)q0.x << 4) + ((uint32_t)q0.y << 20);
  uint32_t b1 = 0x54005400u + ((uint32_t)q0.z << 4) + ((uint32_t)q0.w << 20);
  uint32_t b2 = 0x54005400u + ((uint32_t)q1.x << 4) + ((uint32_t)q1.y << 20);
  uint32_t b3 = 0x54005400u + ((uint32_t)q1.z << 4) + ((uint32_t)q1.w << 20);
  union { s16x8 v; __half2 h2[4]; } w;
  w.h2[0] = __hfma2(*(__half2*)&b0, s2, c2);
  w.h2[1] = __hfma2(*(__half2*)&b1, s2, c2);
  w.h2[2] = __hfma2(*(__half2*)&b2, s2, c2);
  w.h2[3] = __hfma2(*(__half2*)&b3, s2, c2);
  return w.v;
}

// bijective XCD swizzle (m204): hardware id -> logical workgroup id
__device__ __forceinline__ int xcd_swz(int w0, int nwg) {
  const int q = nwg >> 3, r = nwg & 7;
  const int xcd = w0 & 7, idx = w0 >> 3;
  const int base = (xcd < r) ? xcd * (q + 1) : r * (q + 1) + (xcd - r) * q;
  return base + idx;
}

// ---------------------------------------------------------------------------
// Fused gate+up GEMM with T14 pipeline: prefetch Q(t+1)+A(t+1) before MFMA(t).
// Tile 128x128x64, 4 waves, A double-buffered (gload_lds), B reg-staged.
// ---------------------------------------------------------------------------
__global__ __launch_bounds__(256, 2)
void gateup_kernel(const __half* __restrict__ Xh,
                   const int* __restrict__ Qg, const int* __restrict__ Qu,
                   const float* __restrict__ Sg, const float* __restrict__ Zg,
                   const float* __restrict__ Su, const float* __restrict__ Zu,
                   __half* __restrict__ Hout,
                   int mblocks) {
  constexpr int H = 4096, I = 11008, G = 32;
  const int wg = xcd_swz(blockIdx.x, gridDim.x);
  const int nb = wg / mblocks;
  const int mb = wg - nb * mblocks;
  const int m0 = mb * 128, n0 = nb * 128;
  const int tid = threadIdx.x;
  const int lane = tid & 63;
  const int wave = tid >> 6;
  const int wm = (wave >> 1) * 64, wn = (wave & 1) * 64;
  const int l15 = lane & 15, lq = lane >> 4;
  const int rsw = (l15 & 7) << 3;
  const int arow = tid >> 3;
  const int acol = (tid & 7) * 8;
  const int swcol = acol ^ ((arow & 7) << 3);

  __shared__ __half As[2][128][64];
  __shared__ __half Bgs[128][64];
  __shared__ __half Bus[128][64];

  f32x4 accg[4][4], accu[4][4];
#pragma unroll
  for (int i = 0; i < 4; ++i)
#pragma unroll
    for (int j = 0; j < 4; ++j) {
      accg[i][j] = {0.f, 0.f, 0.f, 0.f};
      accu[i][j] = {0.f, 0.f, 0.f, 0.f};
    }

  int4 q[4][2][2];     // prefetched raw weights (spans MFMA phase)
  s16x8 wreg[4][2];    // dequantized, short-lived

  // ---------------- prologue: tile 0 ----------------
#pragma unroll
  for (int c = 0; c < 4; ++c) {
    const __half* src = Xh + (size_t)(m0 + c * 32 + arow) * H + swcol;
    __half* dst = &As[0][0][0] + (size_t)(c * 256 + tid) * 8;
    __builtin_amdgcn_global_load_lds((const __attribute__((address_space(1))) void*)src,
                                     (__attribute__((address_space(3))) void*)dst, 16, 0, 0);
  }
#pragma unroll
  for (int it = 0; it < 4; ++it) {
    const int rg = n0 + it * 32 + arow;
    const int* qpg = Qg + (size_t)rg * H + acol;
    const int* qpu = Qu + (size_t)rg * H + acol;
    q[it][0][0] = *(const int4*)qpg; q[it][0][1] = *(const int4*)(qpg + 4);
    q[it][1][0] = *(const int4*)qpu; q[it][1][1] = *(const int4*)(qpu + 4);
  }
#pragma unroll
  for (int it = 0; it < 4; ++it) {
    const int rg = n0 + it * 32 + arow;
    wreg[it][0] = dq_compute(q[it][0][0], q[it][0][1], Sg[rg * G], Zg[rg * G]);
    wreg[it][1] = dq_compute(q[it][1][0], q[it][1][1], Su[rg * G], Zu[rg * G]);
  }
#pragma unroll
  for (int it = 0; it < 4; ++it) {
    const int r = it * 32 + arow;
    *(s16x8*)&Bgs[r][swcol] = wreg[it][0];
    *(s16x8*)&Bus[r][swcol] = wreg[it][1];
  }
  __syncthreads();

  int p = 0;
  const int nt = H / 64;
  for (int t = 0; t < nt; ++t) {
    const int k1 = (t + 1 < nt) ? (t + 1) * 64 : t * 64;  // clamped next tile
    // ---- issue prefetches for t+1 (latency hides under MFMA(t)) ----
#pragma unroll
    for (int it = 0; it < 4; ++it) {
      const int rg = n0 + it * 32 + arow;
      const int* qpg = Qg + (size_t)rg * H + (k1 + acol);
      const int* qpu = Qu + (size_t)rg * H + (k1 + acol);
      q[it][0][0] = *(const int4*)qpg; q[it][0][1] = *(const int4*)(qpg + 4);
      q[it][1][0] = *(const int4*)qpu; q[it][1][1] = *(const int4*)(qpu + 4);
    }
#pragma unroll
    for (int c = 0; c < 4; ++c) {
      const __half* src = Xh + (size_t)(m0 + c * 32 + arow) * H + (k1 + swcol);
      __half* dst = &As[p ^ 1][0][0] + (size_t)(c * 256 + tid) * 8;
      __builtin_amdgcn_global_load_lds((const __attribute__((address_space(1))) void*)src,
                                       (__attribute__((address_space(3))) void*)dst, 16, 0, 0);
    }
    // ---- MFMA phase on tile t ----
#pragma unroll
    for (int kk = 0; kk < 2; ++kk) {
      const int cbase = (kk * 32 + lq * 8) ^ rsw;
      f16x8 af[4];
#pragma unroll
      for (int i = 0; i < 4; ++i)
        af[i] = *(const f16x8*)&As[p][wm + i * 16 + l15][cbase];
#pragma unroll
      for (int j = 0; j < 4; ++j) {
        f16x8 bg = *(const f16x8*)&Bgs[wn + j * 16 + l15][cbase];
        f16x8 bu = *(const f16x8*)&Bus[wn + j * 16 + l15][cbase];
#pragma unroll
        for (int i = 0; i < 4; ++i) {
          accg[i][j] = __builtin_amdgcn_mfma_f32_16x16x32_f16(af[i], bg, accg[i][j], 0, 0, 0);
          accu[i][j] = __builtin_amdgcn_mfma_f32_16x16x32_f16(af[i], bu, accu[i][j], 0, 0, 0);
        }
      }
    }
    // ---- dequant t+1 (Q arrived during MFMA; s/z loaded here, short-lived) ----
    {
      const int gidx1 = k1 >> 7;
#pragma unroll
      for (int it = 0; it < 4; ++it) {
        const int rg = n0 + it * 32 + arow;
        wreg[it][0] = dq_compute(q[it][0][0], q[it][0][1], Sg[rg * G + gidx1], Zg[rg * G + gidx1]);
        wreg[it][1] = dq_compute(q[it][1][0], q[it][1][1], Su[rg * G + gidx1], Zu[rg * G + gidx1]);
      }
    }
    __syncthreads();  // all waves done reading B(t); A(t+1) drained (landed during MFMA)
#pragma unroll
    for (int it = 0; it < 4; ++it) {
      const int r = it * 32 + arow;
      *(s16x8*)&Bgs[r][swcol] = wreg[it][0];
      *(s16x8*)&Bus[r][swcol] = wreg[it][1];
    }
    __syncthreads();  // B(t+1) visible
    p ^= 1;
  }
  // ---- epilogue: h = silu(g)*u -> fp16 ----
#pragma unroll
  for (int i = 0; i < 4; ++i)
#pragma unroll
    for (int j = 0; j < 4; ++j)
#pragma unroll
      for (int r = 0; r < 4; ++r) {
        const int row = m0 + wm + i * 16 + lq * 4 + r;
        const int col = n0 + wn + j * 16 + l15;
        float g = accg[i][j][r];
        float u = accu[i][j][r];
        float hv = (g / (1.f + __expf(-g))) * u;
        Hout[(size_t)row * I + col] = __float2half(hv);
      }
}

// ---------------------------------------------------------------------------
// Down GEMM: out = h @ Wd^T, same T14 pipeline. K=11008.
// ---------------------------------------------------------------------------
__global__ __launch_bounds__(256, 3)
void down_kernel(const __half* __restrict__ Hin,
                 const int* __restrict__ Qd,
                 const float* __restrict__ Sd, const float* __restrict__ Zd,
                 float* __restrict__ Out,
                 int mblocks) {
  constexpr int K = 11008, N = 4096, G = 86;
  const int wg = xcd_swz(blockIdx.x, gridDim.x);
  const int nb = wg / mblocks;
  const int mb = wg - nb * mblocks;
  const int m0 = mb * 128, n0 = nb * 128;
  const int tid = threadIdx.x;
  const int lane = tid & 63;
  const int wave = tid >> 6;
  const int wm = (wave >> 1) * 64, wn = (wave & 1) * 64;
  const int l15 = lane & 15, lq = lane >> 4;
  const int rsw = (l15 & 7) << 3;
  const int arow = tid >> 3;
  const int acol = (tid & 7) * 8;
  const int swcol = acol ^ ((arow & 7) << 3);

  __shared__ __half As[2][128][64];
  __shared__ __half Bs[128][64];

  f32x4 acc[4][4];
#pragma unroll
  for (int i = 0; i < 4; ++i)
#pragma unroll
    for (int j = 0; j < 4; ++j) acc[i][j] = {0.f, 0.f, 0.f, 0.f};

  int4 q[4][2];
  s16x8 wreg[4];

  // ---------------- prologue ----------------
#pragma unroll
  for (int c = 0; c < 4; ++c) {
    const __half* src = Hin + (size_t)(m0 + c * 32 + arow) * K + swcol;
    __half* dst = &As[0][0][0] + (size_t)(c * 256 + tid) * 8;
    __builtin_amdgcn_global_load_lds((const __attribute__((address_space(1))) void*)src,
                                     (__attribute__((address_space(3))) void*)dst, 16, 0, 0);
  }
#pragma unroll
  for (int it = 0; it < 4; ++it) {
    const int rg = n0 + it * 32 + arow;
    const int* qp = Qd + (size_t)rg * K + acol;
    q[it][0] = *(const int4*)qp; q[it][1] = *(const int4*)(qp + 4);
  }
#pragma unroll
  for (int it = 0; it < 4; ++it) {
    const int rg = n0 + it * 32 + arow;
    wreg[it] = dq_compute(q[it][0], q[it][1], Sd[rg * G], Zd[rg * G]);
  }
#pragma unroll
  for (int it = 0; it < 4; ++it) {
    const int r = it * 32 + arow;
    *(s16x8*)&Bs[r][swcol] = wreg[it];
  }
  __syncthreads();

  int p = 0;
  const int nt = K / 64;
  for (int t = 0; t < nt; ++t) {
    const int k1 = (t + 1 < nt) ? (t + 1) * 64 : t * 64;
#pragma unroll
    for (int it = 0; it < 4; ++it) {
      const int rg = n0 + it * 32 + arow;
      const int* qp = Qd + (size_t)rg * K + (k1 + acol);
      q[it][0] = *(const int4*)qp; q[it][1] = *(const int4*)(qp + 4);
    }
#pragma unroll
    for (int c = 0; c < 4; ++c) {
      const __half* src = Hin + (size_t)(m0 + c * 32 + arow) * K + (k1 + swcol);
      __half* dst = &As[p ^ 1][0][0] + (size_t)(c * 256 + tid) * 8;
      __builtin_amdgcn_global_load_lds((const __attribute__((address_space(1))) void*)src,
                                       (__attribute__((address_space(3))) void*)dst, 16, 0, 0);
    }
#pragma unroll
    for (int kk = 0; kk < 2; ++kk) {
      const int cbase = (kk * 32 + lq * 8) ^ rsw;
      f16x8 af[4];
#pragma unroll
      for (int i = 0; i < 4; ++i)
        af[i] = *(const f16x8*)&As[p][wm + i * 16 + l15][cbase];
#pragma unroll
      for (int j = 0; j < 4; ++j) {
        f16x8 bf = *(const f16x8*)&Bs[wn + j * 16 + l15][cbase];
#pragma unroll
        for (int i = 0; i < 4; ++i)
          acc[i][j] = __builtin_amdgcn_mfma_f32_16x16x32_f16(af[i], bf, acc[i][j], 0, 0, 0);
      }
    }
    {
      const int gidx1 = k1 >> 7;
#pragma unroll
      for (int it = 0; it < 4; ++it) {
        const int rg = n0 + it * 32 + arow;
        wreg[it] = dq_compute(q[it][0], q[it][1], Sd[rg * G + gidx1], Zd[rg * G + gidx1]);
      }
    }
    __syncthreads();
#pragma unroll
    for (int it = 0; it < 4; ++it) {
      const int r = it * 32 + arow;
      *(s16x8*)&Bs[r][swcol] = wreg[it];
    }
    __syncthreads();
    p ^= 1;
  }
#pragma unroll
  for (int i = 0; i < 4; ++i)
#pragma unroll
    for (int j = 0; j < 4; ++j)
#pragma unroll
      for (int r = 0; r < 4; ++r) {
        const int row = m0 + wm + i * 16 + lq * 4 + r;
        const int col = n0 + wn + j * 16 + l15;
        Out[(size_t)row * N + col] = acc[i][j][r];
      }
}

// ---------------------------------------------------------------------------
extern "C" void kernel_launch(void* const* d_in, const int* in_sizes, int n_in,
                              void* d_out, int out_size, void* d_ws, size_t ws_size,
                              hipStream_t stream) {
  const float* x  = (const float*)d_in[0];
  const int* qg   = (const int*)d_in[1];
  const int* qu   = (const int*)d_in[2];
  const int* qd   = (const int*)d_in[3];
  const float* sg = (const float*)d_in[4];
  const float* zg = (const float*)d_in[5];
  const float* su = (const float*)d_in[6];
  const float* zu = (const float*)d_in[7];
  const float* sd = (const float*)d_in[8];
  const float* zd = (const float*)d_in[9];
  float* out = (float*)d_out;

  const int M = 4 * 2048, H = 4096, I = 11008;

  const size_t per_row = (size_t)(H + I) * 2;
  long mc = (long)(ws_size / per_row);
  mc &= ~127L;
  if (mc > M) mc = M;
  if (mc < 128) mc = 128;
  const int Mc = (int)mc;

  __half* wsx = (__half*)d_ws;
  __half* wsh = (__half*)((char*)d_ws + (size_t)Mc * H * 2);

  for (int mbase = 0; mbase < M; mbase += Mc) {
    const int rows = (M - mbase < Mc) ? (M - mbase) : Mc;
    const int mblocks = rows / 128;
    const long n = (long)rows * H;
    cvt_f32_to_f16_kernel<<<1024, 256, 0, stream>>>(x + (size_t)mbase * H, wsx, n);
    gateup_kernel<<<(I / 128) * mblocks, 256, 0, stream>>>(
        wsx, qg, qu, sg, zg, su, zu, wsh, mblocks);
    down_kernel<<<(H / 128) * mblocks, 256, 0, stream>>>(
        wsh, qd, sd, zd, out + (size_t)mbase * H, mblocks);
  }
}